// Round 4
// baseline (104.610 us; speedup 1.0000x reference)
//
#include <hip/hip_runtime.h>
#include <cstdint>
#include <cstddef>

#define Bn 16
#define Hn 512
#define Wn 1024
#define NTOP 2048
#define KMAX 512
#define PAIRCAP 2048
#define SEGS 8
#define SEGCAP 2048
#define FBINS 4096
#define FBASE 126566      // (0x3DCCCCCD>>13); scores in (0.1,1) -> bins [0,3481]
#define KEYSN 4096
#define CPAD 32           // counter padding: 128B apart

// ---------------- Kernel 1: local-max detect + segmented append + fused histogram ----
// Tile 64x16 interior, LDS tile 22x72 (x-aligned for float4). img = gray*mask.
// valid = (img==pool7x7(img)) && img>0.1 (mask>0 implied). One global atomicAdd per
// block reserves a segment range; per-candidate histogram atomics happen at writeback
// so hist matches exactly what is stored.
__global__ __launch_bounds__(256) void detect_kernel(const float* __restrict__ gray,
                                                     const float* __restrict__ mask,
                                                     uint64_t* __restrict__ cand,
                                                     int* __restrict__ counts,
                                                     int* __restrict__ hist_g) {
    __shared__ float s_img[22][72];   // col c <-> gx = x0 + c - 4 (cols 0,71 are pad)
    __shared__ float s_cmax[16][72];
    __shared__ uint64_t s_list[1024];
    __shared__ int s_n, s_base;

    const int x0 = blockIdx.x * 64;
    const int y0 = blockIdx.y * 16;
    const int b  = blockIdx.z;
    const int t  = threadIdx.x;
    const float* gb = gray + (size_t)b * Hn * Wn;
    const float* mb = mask + (size_t)b * Hn * Wn;

    if (t == 0) s_n = 0;

    const bool xedge = (blockIdx.x == 0) || (blockIdx.x == (Wn / 64 - 1));
    if (!xedge) {
        // vectorized: 22 rows x 18 float4 (byte offset of x0-4 is 16B-aligned)
        for (int l = t; l < 22 * 18; l += 256) {
            int r = l / 18, c4 = l % 18;
            int gy = y0 + r - 3;
            float4 v;
            if (gy >= 0 && gy < Hn) {
                const float4* gp = (const float4*)(gb + (size_t)gy * Wn + x0 - 4);
                const float4* mp = (const float4*)(mb + (size_t)gy * Wn + x0 - 4);
                float4 g = gp[c4], m = mp[c4];
                v = make_float4(g.x * m.x, g.y * m.y, g.z * m.z, g.w * m.w);
            } else {
                float ni = -__builtin_inff();
                v = make_float4(ni, ni, ni, ni);
            }
            *(float4*)&s_img[r][c4 * 4] = v;
        }
    } else {
        for (int l = t; l < 22 * 72; l += 256) {
            int r = l / 72, c = l % 72;
            int gy = y0 + r - 3, gx = x0 + c - 4;
            float v = -__builtin_inff();
            if (gy >= 0 && gy < Hn && gx >= 0 && gx < Wn) {
                int o = gy * Wn + gx;
                v = gb[o] * mb[o];
            }
            s_img[r][c] = v;
        }
    }
    __syncthreads();

    // vertical max over 7
    for (int l = t; l < 16 * 72; l += 256) {
        int r = l / 72, c = l % 72;
        float m = s_img[r][c];
#pragma unroll
        for (int d = 1; d < 7; ++d) m = fmaxf(m, s_img[r + d][c]);
        s_cmax[r][c] = m;
    }
    __syncthreads();

    // horizontal max over 7 + validity + LDS append (pixel c at col c+4)
    for (int l = t; l < 16 * 64; l += 256) {
        int r = l >> 6, c = l & 63;
        float p = s_cmax[r][c + 1];
#pragma unroll
        for (int d = 2; d < 8; ++d) p = fmaxf(p, s_cmax[r][c + d]);
        float v = s_img[r + 3][c + 4];
        if (v == p && v > 0.1f) {
            uint32_t idx = (uint32_t)((y0 + r) * Wn + (x0 + c));
            uint64_t key = ((uint64_t)__float_as_uint(v) << 32) | (uint32_t)(~idx);
            int pos = atomicAdd(&s_n, 1);
            if (pos < 1024) s_list[pos] = key;
        }
    }
    __syncthreads();

    int m = s_n; if (m > 1024) m = 1024;
    const int seg = (blockIdx.y * gridDim.x + blockIdx.x) & (SEGS - 1);
    if (t == 0) s_base = atomicAdd(&counts[(b * SEGS + seg) * CPAD], m);
    __syncthreads();
    int base = s_base;
    uint64_t* dst = cand + ((size_t)b * SEGS + seg) * SEGCAP;
    for (int i = t; i < m; i += 256) {
        int d = base + i;
        if (d < SEGCAP) {
            uint64_t k = s_list[i];
            dst[d] = k;
            uint32_t sbits = (uint32_t)(k >> 32);
            int bin = (int)(sbits >> 13) - FBASE;
            bin = bin < 0 ? 0 : (bin > FBINS - 1 ? FBINS - 1 : bin);
            atomicAdd(&hist_g[(size_t)b * FBINS + bin], 1);
        }
    }
}

// ---------------- Kernel 2: scatter sort (precomputed hist) + tie-run NMS + compact --
// One 1024-thread block per batch. Candidates preloaded to registers (one latency
// exposure). Suffix scan of 4096 bins via shfl hierarchy (4 barriers). Scatter to
// sorted-by-bin slots, per-bin insertion sorts, tie-run NMS, shfl-hierarchical
// compaction scan.
__global__ __launch_bounds__(1024) void topk_nms_kernel(const uint64_t* __restrict__ cand,
                                                        const int* __restrict__ counts,
                                                        const int* __restrict__ hist_g,
                                                        float* __restrict__ kp_out,
                                                        float* __restrict__ sc_out) {
    __shared__ uint64_t keys[KEYSN];     // 32 KB
    __shared__ int      curs[FBINS];     // 16 KB (scatter cursors)
    __shared__ int      sfx[FBINS];      // 16 KB (per-bin suffix sums)
    __shared__ int      scanA[64];
    __shared__ uint32_t pairs[PAIRCAP];  // 8 KB
    __shared__ uint8_t  keep[NTOP];      // 2 KB
    __shared__ int      sel[KMAX];       // 2 KB
    __shared__ int      ns[SEGS];
    __shared__ int      misc[4];         // 1: pair count, 2: threshold bin

    const int b = blockIdx.x;
    const int t = threadIdx.x;
    const int lane = t & 63;
    const int w = t >> 6;
    const uint64_t* cb = cand + (size_t)b * SEGS * SEGCAP;

    // issue all candidate loads up front (independent; one vmcnt exposure)
    uint64_t ck[16];
#pragma unroll
    for (int k = 0; k < 16; ++k) ck[k] = cb[t + (k << 10)];

    // this thread's 4 histogram bins
    const int base4 = t << 2;
    const int4 h4 = *(const int4*)(hist_g + (size_t)b * FBINS + base4);

    if (t < SEGS) {
        int v = counts[(b * SEGS + t) * CPAD];
        ns[t] = v > SEGCAP ? SEGCAP : v;
    }
    if (t < 4) misc[t] = 0;
    if (t < KMAX) sel[t] = -1;
    __syncthreads();

    bool cv[16];
#pragma unroll
    for (int k = 0; k < 16; ++k) {
        int i = t + (k << 10);
        cv[k] = (i & (SEGCAP - 1)) < ns[i >> 11];
    }

    // hierarchical suffix scan of loc = sum of own 4 bins
    int loc = h4.x + h4.y + h4.z + h4.w;
    int x = loc;
#pragma unroll
    for (int d = 1; d < 64; d <<= 1) {
        int y = __shfl_down(x, d, 64);
        if (lane + d < 64) x += y;
    }
    if (lane == 0) scanA[w] = x;                 // wave total
    __syncthreads();
    if (w == 0) {
        int v = (lane < 16) ? scanA[lane] : 0;
#pragma unroll
        for (int d = 1; d < 16; d <<= 1) {
            int y = __shfl_down(v, d, 64);
            if (lane + d < 64) v += y;
        }
        if (lane < 16) scanA[lane] = v;          // suffix over wave totals
    }
    __syncthreads();
    const int total = scanA[0];
    const int target = total < NTOP ? total : NTOP;
    const int S_incl = x + ((w < 15) ? scanA[w + 1] : 0);   // suffix incl own bins

    // per-bin suffix sums, scatter cursors, threshold-bin crossing (local test)
    int r = S_incl - loc;                        // sfx[base4+4]
    int s3 = r + h4.w;
    int s2 = s3 + h4.z;
    int s1 = s2 + h4.y;
    int s0 = s1 + h4.x;
    sfx[base4]     = s0;
    sfx[base4 + 1] = s1;
    sfx[base4 + 2] = s2;
    sfx[base4 + 3] = s3;
    curs[base4]     = s1;
    curs[base4 + 1] = s2;
    curs[base4 + 2] = s3;
    curs[base4 + 3] = r;
    // T = unique j with sfx[j] >= target && (j==last || sfx[j+1] < target)
    if (s0 >= target && s1 < target) misc[2] = base4;
    if (s1 >= target && s2 < target) misc[2] = base4 + 1;
    if (s2 >= target && s3 < target) misc[2] = base4 + 2;
    if (s3 >= target && (base4 + 3 == FBINS - 1 || r < target)) misc[2] = base4 + 3;
    __syncthreads();
    const int T = misc[2];

    // scatter selected bins to sorted-by-bin slots (register-resident candidates)
#pragma unroll
    for (int k = 0; k < 16; ++k) {
        if (cv[k]) {
            uint32_t sbits = (uint32_t)(ck[k] >> 32);
            int bin = (int)(sbits >> 13) - FBASE;
            bin = bin < 0 ? 0 : (bin > FBINS - 1 ? FBINS - 1 : bin);
            if (bin >= T) {
                int pos = atomicAdd(&curs[bin], 1);
                if (pos < KEYSN) keys[pos] = ck[k];
            }
        }
    }
    // zero-fill [cnt, NTOP): disjoint from scatter range [0, cnt) -> same phase
    int cnt = sfx[T]; if (cnt > KEYSN) cnt = KEYSN;
    for (int i = t; i < NTOP; i += 1024)
        if (i >= cnt) keys[i] = 0ull;
    __syncthreads();

    // per-bin insertion sorts (descending by key: score desc, index asc)
    for (int j = t; j < FBINS; j += 1024) {
        if (j >= T) {
            int a0 = (j + 1 < FBINS) ? sfx[j + 1] : 0;
            int e0 = sfx[j];
            if (a0 > KEYSN) a0 = KEYSN;
            if (e0 > KEYSN) e0 = KEYSN;
            for (int a = a0 + 1; a < e0; ++a) {
                uint64_t v = keys[a]; int q = a - 1;
                while (q >= a0 && keys[q] < v) { keys[q + 1] = keys[q]; --q; }
                keys[q + 1] = v;
            }
        }
    }
    __syncthreads();

    // keep init + conflict pairs (only within equal-score runs: two valid candidates
    // with dist<3 lie in each other's 7x7 window => equal pooled max => tied)
    for (int j = t; j < NTOP; j += 1024) {
        uint32_t s = (uint32_t)(keys[j] >> 32);
        keep[j] = (s != 0u) ? 1 : 0;
        if (s) {
            uint32_t idx = ~(uint32_t)keys[j];
            int xq = (int)(idx & (Wn - 1)), yq = (int)(idx >> 10);
            for (int i = j - 1; i >= 0 && (uint32_t)(keys[i] >> 32) == s; --i) {
                uint32_t idx2 = ~(uint32_t)keys[i];
                int dx = xq - (int)(idx2 & (Wn - 1));
                int dy = yq - (int)(idx2 >> 10);
                if (dx * dx + dy * dy < 9) {
                    int p = atomicAdd(&misc[1], 1);
                    if (p < PAIRCAP) pairs[p] = ((uint32_t)j << 16) | (uint32_t)i;
                }
            }
        }
    }
    __syncthreads();

    if (t == 0) {   // sequential greedy resolve (tiny; canonical order via sort)
        int pc = misc[1]; if (pc > PAIRCAP) pc = PAIRCAP;
        for (int a = 1; a < pc; ++a) {
            uint32_t v = pairs[a]; int q = a - 1;
            while (q >= 0 && pairs[q] > v) { pairs[q + 1] = pairs[q]; --q; }
            pairs[q + 1] = v;
        }
        for (int a = 0; a < pc; ++a) {
            int j = (int)(pairs[a] >> 16), i = (int)(pairs[a] & 0xFFFF);
            if (keep[i]) keep[j] = 0;
        }
    }
    __syncthreads();

    // compaction prefix scan (shfl hierarchy), select first 512 kept
    int j0 = 2 * t, j1 = j0 + 1;
    int k0 = keep[j0], k1 = keep[j1];
    int sum = k0 + k1;
    int xp = sum;
#pragma unroll
    for (int d = 1; d < 64; d <<= 1) {
        int y = __shfl_up(xp, d, 64);
        if (lane >= d) xp += y;
    }
    if (lane == 63) scanA[w] = xp;               // wave total
    __syncthreads();
    if (w == 0) {
        int v = (lane < 16) ? scanA[lane] : 0;
#pragma unroll
        for (int d = 1; d < 16; d <<= 1) {
            int y = __shfl_up(v, d, 64);
            if (lane >= d) v += y;
        }
        if (lane < 16) scanA[lane] = v;          // prefix over wave totals
    }
    __syncthreads();
    int pre = xp + ((w > 0) ? scanA[w - 1] : 0); // inclusive prefix
    int ex = pre - sum;
    if (k0 && ex < KMAX) sel[ex] = j0;
    if (k1 && (ex + k0) < KMAX) sel[ex + k0] = j1;
    __syncthreads();

    if (t < KMAX) {
        int jj = sel[t];
        float xo = 0.f, yo = 0.f, so = 0.f;
        if (jj >= 0) {
            uint32_t idx = ~(uint32_t)keys[jj];
            xo = (float)(idx & (Wn - 1));
            yo = (float)(idx >> 10);
            so = __uint_as_float((uint32_t)(keys[jj] >> 32));
        }
        kp_out[(size_t)b * KMAX * 2 + 2 * t]     = xo;
        kp_out[(size_t)b * KMAX * 2 + 2 * t + 1] = yo;
        sc_out[(size_t)b * KMAX + t]             = so;
    }
}

extern "C" void kernel_launch(void* const* d_in, const int* in_sizes, int n_in,
                              void* d_out, int out_size, void* d_ws, size_t ws_size,
                              hipStream_t stream) {
    const float* gray = (const float*)d_in[0];
    const float* mask = (const float*)d_in[1];
    float* out = (float*)d_out;
    float* kp_out = out;                        // 16*512*2
    float* sc_out = out + (size_t)Bn * KMAX * 2;

    int* counts = (int*)d_ws;                             // 16 KiB (padded counters)
    int* hist_g = (int*)((char*)d_ws + 16384);            // 16*4096*4 = 256 KiB
    uint64_t* cand = (uint64_t*)((char*)d_ws + 16384 + 262144);  // 2 MiB

    hipMemsetAsync(d_ws, 0, 16384 + 262144, stream);

    dim3 g1(Wn / 64, Hn / 16, Bn);              // (16, 32, 16)
    detect_kernel<<<g1, 256, 0, stream>>>(gray, mask, cand, counts, hist_g);

    topk_nms_kernel<<<Bn, 1024, 0, stream>>>(cand, counts, hist_g, kp_out, sc_out);
}